// Round 3
// baseline (1386.525 us; speedup 1.0000x reference)
//
#include <hip/hip_runtime.h>
#include <hip/hip_bf16.h>
#include <math.h>

#define B_ 4
#define L_ 1024
#define H_ 8
#define E_ 64
#define N_ 1024
#define NF_ 513            // rfft bins for N=1024
#define SCALE_ 0.125f      // 1/sqrt(E)
#define HE_ (H_ * E_)

__device__ __forceinline__ int brev10(int x) {
    return (int)(__brev((unsigned)x) >> 22);
}

// Compact per-stage twiddles: stage with half-span S=2^ls stores its S entries
// at offset S-1, entry pos = (cos, sin)(pi*pos/S). Reads are consecutive or
// broadcast -> conflict-free. 1023 entries total.
__device__ __forceinline__ void fill_tw(float2* tw, int t) {
    for (int i = t; i < 1023; i += 256) {
        const int v = i + 1;
        const int ls = 31 - __clz(v);
        const int S = 1 << ls;
        float sv, cv;
        sincosf(3.14159265358979323846f * (float)(v - S) / (float)S, &sv, &cv);
        tw[i] = make_float2(cv, sv);
    }
}

// Radix-2 DIT: bit-reversed input -> natural output. dir=-1 fwd, +1 inv (unnorm).
// 256 threads, 1024 points, interleaved float2. Ends with __syncthreads().
__device__ __forceinline__ void fft_dit(float2* z, const float2* tw, int t, float dir) {
    #pragma unroll
    for (int ls = 0; ls <= 9; ++ls) {
        const int S = 1 << ls;
        #pragma unroll
        for (int jj = 0; jj < 2; ++jj) {
            const int j = t + jj * 256;
            const int pos = j & (S - 1);
            const int i1 = ((j >> ls) << (ls + 1)) + pos;
            const int i2 = i1 + S;
            const float2 w = tw[S - 1 + pos];
            const float wr = w.x, wi = dir * w.y;
            const float2 u = z[i1], v = z[i2];
            const float tr = v.x * wr - v.y * wi;
            const float ti = v.x * wi + v.y * wr;
            z[i1] = make_float2(u.x + tr, u.y + ti);
            z[i2] = make_float2(u.x - tr, u.y - ti);
        }
        __syncthreads();
    }
}

// Radix-2 DIF: natural input -> bit-reversed output. dir=-1 fwd, +1 inv (unnorm).
__device__ __forceinline__ void fft_dif(float2* z, const float2* tw, int t, float dir) {
    #pragma unroll
    for (int ls = 9; ls >= 0; --ls) {
        const int S = 1 << ls;
        #pragma unroll
        for (int jj = 0; jj < 2; ++jj) {
            const int j = t + jj * 256;
            const int pos = j & (S - 1);
            const int i1 = ((j >> ls) << (ls + 1)) + pos;
            const int i2 = i1 + S;
            const float2 w = tw[S - 1 + pos];
            const float wr = w.x, wi = dir * w.y;
            const float2 u = z[i1], v = z[i2];
            z[i1] = make_float2(u.x + v.x, u.y + v.y);
            const float dr = u.x - v.x, di = u.y - v.y;
            z[i2] = make_float2(dr * wr - di * wi, dr * wi + di * wr);
        }
        __syncthreads();
    }
}

// Kernel 0: reciprocal L2 norms of all q-rows and k-rows.
__global__ __launch_bounds__(256) void k_norms(const float* __restrict__ Q,
                                               const float* __restrict__ K,
                                               float* __restrict__ qninv,
                                               float* __restrict__ kninv) {
    const int n = B_ * L_ * H_;
    const int i = blockIdx.x * 256 + threadIdx.x;
    if (i >= 2 * n) return;
    const float* p = (i < n) ? (Q + (size_t)i * E_) : (K + (size_t)(i - n) * E_);
    float ss = 0.0f;
    #pragma unroll
    for (int j = 0; j < 16; ++j) {
        const float4 v = *(const float4*)(p + j * 4);
        ss += v.x * v.x + v.y * v.y + v.z * v.z + v.w * v.w;
    }
    const float r = rsqrtf(ss);
    if (i < n) qninv[i] = r; else kninv[i - n] = r;
}

// Kernel 1: block = one (b,h) x 16 q-rows. Two passes of 8 rows:
// dots (K per-lane from global, Q uniform s_load) -> 4 packed pair-FFTs per pass
// (DIT, bitrev input written linearly since thread owns s'=brev10(slot))
// -> per-row softmax of 513 natural-order bins -> s_acc -> atomicAdd G.
// launch_bounds (256,2): VGPR cap 256 -- round-2's (256,4) made the allocator
// target 64 VGPRs and spill ~1.7 KB/thread to scratch (895 MB WRITE_SIZE).
__global__ __launch_bounds__(256, 2) void k_qkfft(const float* __restrict__ Q,
                                                  const float* __restrict__ K,
                                                  const float* __restrict__ qninv,
                                                  const float* __restrict__ kninv,
                                                  float* __restrict__ G) {
    __shared__ float2 s_z[1024];    // 8 KB FFT buffer (interleaved)
    __shared__ float2 s_tw[1024];   // 8 KB compact twiddles
    __shared__ float s_acc[NF_];
    __shared__ float s_red[16];

    const int t = threadIdx.x;
    const int bid = blockIdx.x;
    const int bh = bid >> 6;        // consecutive blocks share (b,h) -> L2 reuse of K
    const int chunk = bid & 63;
    const int b = bh >> 3, h = bh & 7;
    const int l0 = chunk * 16;

    fill_tw(s_tw, t);
    for (int kk = t; kk < NF_; kk += 256) s_acc[kk] = 0.0f;

    // thread's 4 source indices s' = brev10(slot), slot = sb*256+t  (so the
    // sim store into the DIT input buffer is linear / conflict-free)
    int sp[4];
    float knv[4];
    #pragma unroll
    for (int sb = 0; sb < 4; ++sb) {
        sp[sb] = brev10(sb * 256 + t);
        knv[sb] = kninv[((size_t)b * L_ + sp[sb]) * H_ + h];
    }
    __syncthreads();

    #pragma unroll 1
    for (int pp = 0; pp < 2; ++pp) {
        const float* qbase = Q + ((size_t)b * L_ + l0 + pp * 8) * HE_ + h * E_;

        float acc[4][8];
        #pragma unroll
        for (int sb = 0; sb < 4; ++sb)
            #pragma unroll
            for (int r = 0; r < 8; ++r) acc[sb][r] = 0.0f;

        #pragma unroll
        for (int sbg = 0; sbg < 2; ++sbg) {
            const int sa = 2 * sbg, sbn = 2 * sbg + 1;
            const float* kap = K + ((size_t)b * L_ + sp[sa]) * HE_ + h * E_;
            const float* kbp = K + ((size_t)b * L_ + sp[sbn]) * HE_ + h * E_;
            #pragma unroll
            for (int ec = 0; ec < 4; ++ec) {
                const float4 ka0 = *(const float4*)(kap + ec * 16 + 0);
                const float4 ka1 = *(const float4*)(kap + ec * 16 + 4);
                const float4 ka2 = *(const float4*)(kap + ec * 16 + 8);
                const float4 ka3 = *(const float4*)(kap + ec * 16 + 12);
                const float4 kb0 = *(const float4*)(kbp + ec * 16 + 0);
                const float4 kb1 = *(const float4*)(kbp + ec * 16 + 4);
                const float4 kb2 = *(const float4*)(kbp + ec * 16 + 8);
                const float4 kb3 = *(const float4*)(kbp + ec * 16 + 12);
                #pragma unroll
                for (int r = 0; r < 8; ++r) {
                    const float* qp = qbase + r * HE_ + ec * 16;   // uniform -> s_load
                    const float4 q0 = *(const float4*)(qp + 0);
                    const float4 q1 = *(const float4*)(qp + 4);
                    const float4 q2 = *(const float4*)(qp + 8);
                    const float4 q3 = *(const float4*)(qp + 12);
                    acc[sa][r] += q0.x * ka0.x + q0.y * ka0.y + q0.z * ka0.z + q0.w * ka0.w
                                + q1.x * ka1.x + q1.y * ka1.y + q1.z * ka1.z + q1.w * ka1.w
                                + q2.x * ka2.x + q2.y * ka2.y + q2.z * ka2.z + q2.w * ka2.w
                                + q3.x * ka3.x + q3.y * ka3.y + q3.z * ka3.z + q3.w * ka3.w;
                    acc[sbn][r] += q0.x * kb0.x + q0.y * kb0.y + q0.z * kb0.z + q0.w * kb0.w
                                 + q1.x * kb1.x + q1.y * kb1.y + q1.z * kb1.z + q1.w * kb1.w
                                 + q2.x * kb2.x + q2.y * kb2.y + q2.z * kb2.z + q2.w * kb2.w
                                 + q3.x * kb3.x + q3.y * kb3.y + q3.z * kb3.z + q3.w * kb3.w;
                }
            }
        }

        float qn[8];
        #pragma unroll
        for (int r = 0; r < 8; ++r)
            qn[r] = qninv[((size_t)b * L_ + l0 + pp * 8 + r) * H_ + h];  // uniform

        #pragma unroll 1
        for (int pr = 0; pr < 4; ++pr) {
            __syncthreads();   // prior extraction/s_red reads complete
            #pragma unroll
            for (int sb = 0; sb < 4; ++sb) {
                const float sA = __expf(acc[sb][2 * pr]     * qn[2 * pr]     * knv[sb]);
                const float sB = __expf(acc[sb][2 * pr + 1] * qn[2 * pr + 1] * knv[sb]);
                s_z[sb * 256 + t] = make_float2(sA, sB);
            }
            __syncthreads();
            fft_dit(s_z, s_tw, t, -1.0f);   // natural-order X

            // Re F_A[k] = (ReX[k]+ReX[N-k])/2 ; Re F_B[k] = (ImX[k]+ImX[N-k])/2
            const float2 X0  = s_z[t];
            const float2 X0n = s_z[(N_ - t) & (N_ - 1)];
            const float2 X1  = s_z[t + 256];
            const float2 X1n = s_z[768 - t];
            const float a0 = SCALE_ * 0.5f * (X0.x + X0n.x);
            const float b0 = SCALE_ * 0.5f * (X0.y + X0n.y);
            const float a1 = SCALE_ * 0.5f * (X1.x + X1n.x);
            const float b1 = SCALE_ * 0.5f * (X1.y + X1n.y);
            float a2 = -1e30f, b2 = -1e30f;
            if (t == 0) {
                const float2 Xm = s_z[512];
                a2 = SCALE_ * Xm.x;
                b2 = SCALE_ * Xm.y;
            }

            float mA = fmaxf(fmaxf(a0, a1), a2);
            float mB = fmaxf(fmaxf(b0, b1), b2);
            #pragma unroll
            for (int off = 32; off > 0; off >>= 1) {
                mA = fmaxf(mA, __shfl_xor(mA, off));
                mB = fmaxf(mB, __shfl_xor(mB, off));
            }
            const int lane = t & 63, wid = t >> 6;
            if (lane == 0) { s_red[wid] = mA; s_red[4 + wid] = mB; }
            __syncthreads();
            mA = fmaxf(fmaxf(s_red[0], s_red[1]), fmaxf(s_red[2], s_red[3]));
            mB = fmaxf(fmaxf(s_red[4], s_red[5]), fmaxf(s_red[6], s_red[7]));

            const float pA0 = __expf(a0 - mA), pA1 = __expf(a1 - mA);
            const float pB0 = __expf(b0 - mB), pB1 = __expf(b1 - mB);
            const float pA2 = (t == 0) ? __expf(a2 - mA) : 0.0f;
            const float pB2 = (t == 0) ? __expf(b2 - mB) : 0.0f;
            float sA = pA0 + pA1 + pA2, sB = pB0 + pB1 + pB2;
            #pragma unroll
            for (int off = 32; off > 0; off >>= 1) {
                sA += __shfl_xor(sA, off);
                sB += __shfl_xor(sB, off);
            }
            __syncthreads();
            if (lane == 0) { s_red[8 + wid] = sA; s_red[12 + wid] = sB; }
            __syncthreads();
            sA = s_red[8] + s_red[9] + s_red[10] + s_red[11];
            sB = s_red[12] + s_red[13] + s_red[14] + s_red[15];
            const float iA = 1.0f / sA, iB = 1.0f / sB;

            s_acc[t]       += pA0 * iA + pB0 * iB;
            s_acc[t + 256] += pA1 * iA + pB1 * iB;
            if (t == 0) s_acc[512] += pA2 * iA + pB2 * iB;
        }
    }
    __syncthreads();

    float* Gp = G + (size_t)bh * NF_;
    for (int kk = t; kk < NF_; kk += 256) atomicAdd(&Gp[kk], s_acc[kk]);
}

// Kernel 2: A[b,h,:] = softmax(G[b,h,:]) over 513 bins.
__global__ __launch_bounds__(256) void k_softA(const float* __restrict__ G,
                                               float* __restrict__ A) {
    __shared__ float s_red[16];
    const int bh = blockIdx.x, t = threadIdx.x;
    const float* Gp = G + (size_t)bh * NF_;
    const float g0 = Gp[t];
    const float g1 = Gp[t + 256];
    const float g2 = (t == 0) ? Gp[512] : -1e30f;
    float m = fmaxf(fmaxf(g0, g1), g2);
    #pragma unroll
    for (int off = 32; off > 0; off >>= 1) m = fmaxf(m, __shfl_xor(m, off));
    const int lane = t & 63, wid = t >> 6;
    if (lane == 0) s_red[wid] = m;
    __syncthreads();
    m = fmaxf(fmaxf(s_red[0], s_red[1]), fmaxf(s_red[2], s_red[3]));
    const float p0 = __expf(g0 - m), p1 = __expf(g1 - m);
    const float p2 = (t == 0) ? __expf(g2 - m) : 0.0f;
    float s = p0 + p1 + p2;
    #pragma unroll
    for (int off = 32; off > 0; off >>= 1) s += __shfl_xor(s, off);
    __syncthreads();
    if (lane == 0) s_red[4 + wid] = s;
    __syncthreads();
    s = s_red[4] + s_red[5] + s_red[6] + s_red[7];
    const float inv = 1.0f / s;
    float* Ap = A + (size_t)bh * NF_;
    Ap[t] = p0 * inv;
    Ap[t + 256] = p1 * inv;
    if (t == 0) Ap[512] = p2 * inv;
}

// Kernel 3: block = one (b,h) x 2 e-channels. Stage V at bitrev positions,
// DIT fwd -> natural X; Hermitian manipulation in natural order (conflict-free);
// DIF inverse (natural in -> bitrev out); write Out[l=brev10(pos)].
__global__ __launch_bounds__(256) void k_vfft(const float* __restrict__ V,
                                              const float* __restrict__ A,
                                              float* __restrict__ Out) {
    __shared__ float2 s_z[1024];
    __shared__ float2 s_w[1024];
    __shared__ float2 s_tw[1024];
    __shared__ float s_A[NF_];

    const int t = threadIdx.x;
    const int bid = blockIdx.x;
    const int bh = bid >> 5, ep = bid & 31;
    const int b = bh >> 3, h = bh & 7;
    const int e0 = ep * 2;

    fill_tw(s_tw, t);
    for (int kk = t; kk < NF_; kk += 256) s_A[kk] = A[(size_t)bh * NF_ + kk];
    #pragma unroll
    for (int jj = 0; jj < 4; ++jj) {
        const int s = jj * 256 + t;
        const float* vp = V + (((size_t)b * L_ + s) * H_ + h) * E_ + e0;
        s_z[brev10(s)] = make_float2(vp[0], vp[1]);
    }
    __syncthreads();

    fft_dit(s_z, s_tw, t, -1.0f);   // natural-order X

    #pragma unroll
    for (int jj = 0; jj < 4; ++jj) {
        const int k = jj * 256 + t;
        const int m = (k <= 512) ? k : (N_ - k);
        const float sgn = (k <= 512) ? 1.0f : -1.0f;
        const int mp = (N_ - m) & (N_ - 1);
        const float2 X1 = s_z[m];
        const float2 X2 = s_z[mp];
        const float reV1 = 0.5f * (X1.x + X2.x);
        const float imV1 = 0.5f * (X1.y - X2.y);
        const float reV2 = 0.5f * (X1.y + X2.y);
        const float imV2 = 0.5f * (X2.x - X1.x);
        const float a = s_A[m];
        s_w[k] = make_float2(a * reV1 - sgn * imV2, sgn * imV1 + a * reV2);
    }
    __syncthreads();

    fft_dif(s_w, s_tw, t, +1.0f);   // unnormalized inverse, bitrev output

    const float invN = 1.0f / (float)N_;
    #pragma unroll
    for (int jj = 0; jj < 4; ++jj) {
        const int p = jj * 256 + t;
        const int l = brev10(p);
        const size_t o = (((size_t)b * L_ + l) * E_ + e0) * H_ + h;
        Out[o] = s_w[p].x * invN;        // e0   -> Re
        Out[o + H_] = s_w[p].y * invN;   // e0+1 -> Im
    }
}

extern "C" void kernel_launch(void* const* d_in, const int* in_sizes, int n_in,
                              void* d_out, int out_size, void* d_ws, size_t ws_size,
                              hipStream_t stream) {
    const float* Q = (const float*)d_in[0];
    const float* K = (const float*)d_in[1];
    const float* V = (const float*)d_in[2];
    float* out = (float*)d_out;

    float* ws = (float*)d_ws;
    float* qninv = ws;                       // B*L*H
    float* kninv = qninv + B_ * L_ * H_;     // B*L*H
    float* G     = kninv + B_ * L_ * H_;     // B*H*NF
    float* A     = G + B_ * H_ * NF_;        // B*H*NF

    hipMemsetAsync(G, 0, (size_t)B_ * H_ * NF_ * sizeof(float), stream);
    k_norms<<<(2 * B_ * L_ * H_ + 255) / 256, 256, 0, stream>>>(Q, K, qninv, kninv);
    k_qkfft<<<B_ * H_ * (L_ / 16), 256, 0, stream>>>(Q, K, qninv, kninv, G);
    k_softA<<<B_ * H_, 256, 0, stream>>>(G, A);
    k_vfft<<<B_ * H_ * (E_ / 2), 256, 0, stream>>>(V, A, out);
}

// Round 4
// 646.617 us; speedup vs baseline: 2.1443x; 2.1443x over previous
//
#include <hip/hip_runtime.h>
#include <hip/hip_bf16.h>
#include <math.h>

#define B_ 4
#define L_ 1024
#define H_ 8
#define E_ 64
#define N_ 1024
#define NF_ 513            // rfft bins for N=1024
#define SCALE_ 0.125f      // 1/sqrt(E)
#define HE_ (H_ * E_)

__device__ __forceinline__ int brev10(int x) {
    return (int)(__brev((unsigned)x) >> 22);
}

// Compact per-stage twiddles: stage with half-span S=2^ls stores its S entries
// at offset S-1, entry pos = (cos, sin)(pi*pos/S). Reads are consecutive or
// broadcast -> conflict-free. 1023 entries total.
__device__ __forceinline__ void fill_tw(float2* tw, int t) {
    for (int i = t; i < 1023; i += 256) {
        const int v = i + 1;
        const int ls = 31 - __clz(v);
        const int S = 1 << ls;
        float sv, cv;
        sincosf(3.14159265358979323846f * (float)(v - S) / (float)S, &sv, &cv);
        tw[i] = make_float2(cv, sv);
    }
}

// Radix-2 DIT: bit-reversed input -> natural output. dir=-1 fwd, +1 inv (unnorm).
// 256 threads, 1024 points, interleaved float2. Ends with __syncthreads().
__device__ __forceinline__ void fft_dit(float2* z, const float2* tw, int t, float dir) {
    #pragma unroll
    for (int ls = 0; ls <= 9; ++ls) {
        const int S = 1 << ls;
        #pragma unroll
        for (int jj = 0; jj < 2; ++jj) {
            const int j = t + jj * 256;
            const int pos = j & (S - 1);
            const int i1 = ((j >> ls) << (ls + 1)) + pos;
            const int i2 = i1 + S;
            const float2 w = tw[S - 1 + pos];
            const float wr = w.x, wi = dir * w.y;
            const float2 u = z[i1], v = z[i2];
            const float tr = v.x * wr - v.y * wi;
            const float ti = v.x * wi + v.y * wr;
            z[i1] = make_float2(u.x + tr, u.y + ti);
            z[i2] = make_float2(u.x - tr, u.y - ti);
        }
        __syncthreads();
    }
}

// Radix-2 DIF: natural input -> bit-reversed output. dir=-1 fwd, +1 inv (unnorm).
__device__ __forceinline__ void fft_dif(float2* z, const float2* tw, int t, float dir) {
    #pragma unroll
    for (int ls = 9; ls >= 0; --ls) {
        const int S = 1 << ls;
        #pragma unroll
        for (int jj = 0; jj < 2; ++jj) {
            const int j = t + jj * 256;
            const int pos = j & (S - 1);
            const int i1 = ((j >> ls) << (ls + 1)) + pos;
            const int i2 = i1 + S;
            const float2 w = tw[S - 1 + pos];
            const float wr = w.x, wi = dir * w.y;
            const float2 u = z[i1], v = z[i2];
            z[i1] = make_float2(u.x + v.x, u.y + v.y);
            const float dr = u.x - v.x, di = u.y - v.y;
            z[i2] = make_float2(dr * wr - di * wi, dr * wi + di * wr);
        }
        __syncthreads();
    }
}

// Kernel 0: reciprocal L2 norms of all q-rows and k-rows.
__global__ __launch_bounds__(256) void k_norms(const float* __restrict__ Q,
                                               const float* __restrict__ K,
                                               float* __restrict__ qninv,
                                               float* __restrict__ kninv) {
    const int n = B_ * L_ * H_;
    const int i = blockIdx.x * 256 + threadIdx.x;
    if (i >= 2 * n) return;
    const float* p = (i < n) ? (Q + (size_t)i * E_) : (K + (size_t)(i - n) * E_);
    float ss = 0.0f;
    #pragma unroll
    for (int j = 0; j < 16; ++j) {
        const float4 v = *(const float4*)(p + j * 4);
        ss += v.x * v.x + v.y * v.y + v.z * v.z + v.w * v.w;
    }
    const float r = rsqrtf(ss);
    if (i < n) qninv[i] = r; else kninv[i - n] = r;
}

// Kernel 1: block = one (b,h) x 16 q-rows. Two passes of 8 rows (pp loop
// unroll 1 is safe: acc lives entirely inside the pass body and the pr loop
// is FULLY unrolled -> all acc indices compile-time static; round-3's
// "#pragma unroll 1" on pr demoted acc to scratch = 1.2 GB spill traffic).
__global__ __launch_bounds__(256, 2) void k_qkfft(const float* __restrict__ Q,
                                                  const float* __restrict__ K,
                                                  const float* __restrict__ qninv,
                                                  const float* __restrict__ kninv,
                                                  float* __restrict__ G) {
    __shared__ float2 s_z[1024];    // 8 KB FFT buffer (interleaved)
    __shared__ float2 s_tw[1024];   // 8 KB compact twiddles
    __shared__ float s_acc[NF_];
    __shared__ float s_red[16];

    const int t = threadIdx.x;
    const int bid = blockIdx.x;
    const int bh = bid >> 6;        // consecutive blocks share (b,h) -> L2 reuse of K
    const int chunk = bid & 63;
    const int b = bh >> 3, h = bh & 7;
    const int l0 = chunk * 16;

    fill_tw(s_tw, t);
    for (int kk = t; kk < NF_; kk += 256) s_acc[kk] = 0.0f;

    // thread's 4 source indices s' = brev10(slot), slot = sb*256+t  (so the
    // sim store into the DIT input buffer is linear / conflict-free)
    int sp[4];
    float knv[4];
    #pragma unroll
    for (int sb = 0; sb < 4; ++sb) {
        sp[sb] = brev10(sb * 256 + t);
        knv[sb] = kninv[((size_t)b * L_ + sp[sb]) * H_ + h];
    }
    __syncthreads();

    #pragma unroll 1
    for (int pp = 0; pp < 2; ++pp) {
        const float* qbase = Q + ((size_t)b * L_ + l0 + pp * 8) * HE_ + h * E_;

        float acc[4][8];
        #pragma unroll
        for (int sb = 0; sb < 4; ++sb)
            #pragma unroll
            for (int r = 0; r < 8; ++r) acc[sb][r] = 0.0f;

        #pragma unroll
        for (int sbg = 0; sbg < 2; ++sbg) {
            const int sa = 2 * sbg, sbn = 2 * sbg + 1;
            const float* kap = K + ((size_t)b * L_ + sp[sa]) * HE_ + h * E_;
            const float* kbp = K + ((size_t)b * L_ + sp[sbn]) * HE_ + h * E_;
            #pragma unroll
            for (int ec = 0; ec < 4; ++ec) {
                const float4 ka0 = *(const float4*)(kap + ec * 16 + 0);
                const float4 ka1 = *(const float4*)(kap + ec * 16 + 4);
                const float4 ka2 = *(const float4*)(kap + ec * 16 + 8);
                const float4 ka3 = *(const float4*)(kap + ec * 16 + 12);
                const float4 kb0 = *(const float4*)(kbp + ec * 16 + 0);
                const float4 kb1 = *(const float4*)(kbp + ec * 16 + 4);
                const float4 kb2 = *(const float4*)(kbp + ec * 16 + 8);
                const float4 kb3 = *(const float4*)(kbp + ec * 16 + 12);
                #pragma unroll
                for (int r = 0; r < 8; ++r) {
                    const float* qp = qbase + r * HE_ + ec * 16;   // uniform -> s_load
                    const float4 q0 = *(const float4*)(qp + 0);
                    const float4 q1 = *(const float4*)(qp + 4);
                    const float4 q2 = *(const float4*)(qp + 8);
                    const float4 q3 = *(const float4*)(qp + 12);
                    acc[sa][r] += q0.x * ka0.x + q0.y * ka0.y + q0.z * ka0.z + q0.w * ka0.w
                                + q1.x * ka1.x + q1.y * ka1.y + q1.z * ka1.z + q1.w * ka1.w
                                + q2.x * ka2.x + q2.y * ka2.y + q2.z * ka2.z + q2.w * ka2.w
                                + q3.x * ka3.x + q3.y * ka3.y + q3.z * ka3.z + q3.w * ka3.w;
                    acc[sbn][r] += q0.x * kb0.x + q0.y * kb0.y + q0.z * kb0.z + q0.w * kb0.w
                                 + q1.x * kb1.x + q1.y * kb1.y + q1.z * kb1.z + q1.w * kb1.w
                                 + q2.x * kb2.x + q2.y * kb2.y + q2.z * kb2.z + q2.w * kb2.w
                                 + q3.x * kb3.x + q3.y * kb3.y + q3.z * kb3.z + q3.w * kb3.w;
                }
            }
        }

        float qn[8];
        #pragma unroll
        for (int r = 0; r < 8; ++r)
            qn[r] = qninv[((size_t)b * L_ + l0 + pp * 8 + r) * H_ + h];  // uniform

        #pragma unroll
        for (int pr = 0; pr < 4; ++pr) {
            __syncthreads();   // prior extraction/s_red reads complete
            #pragma unroll
            for (int sb = 0; sb < 4; ++sb) {
                const float sA = __expf(acc[sb][2 * pr]     * qn[2 * pr]     * knv[sb]);
                const float sB = __expf(acc[sb][2 * pr + 1] * qn[2 * pr + 1] * knv[sb]);
                s_z[sb * 256 + t] = make_float2(sA, sB);
            }
            __syncthreads();
            fft_dit(s_z, s_tw, t, -1.0f);   // natural-order X

            // Re F_A[k] = (ReX[k]+ReX[N-k])/2 ; Re F_B[k] = (ImX[k]+ImX[N-k])/2
            const float2 X0  = s_z[t];
            const float2 X0n = s_z[(N_ - t) & (N_ - 1)];
            const float2 X1  = s_z[t + 256];
            const float2 X1n = s_z[768 - t];
            const float a0 = SCALE_ * 0.5f * (X0.x + X0n.x);
            const float b0 = SCALE_ * 0.5f * (X0.y + X0n.y);
            const float a1 = SCALE_ * 0.5f * (X1.x + X1n.x);
            const float b1 = SCALE_ * 0.5f * (X1.y + X1n.y);
            float a2 = -1e30f, b2 = -1e30f;
            if (t == 0) {
                const float2 Xm = s_z[512];
                a2 = SCALE_ * Xm.x;
                b2 = SCALE_ * Xm.y;
            }

            float mA = fmaxf(fmaxf(a0, a1), a2);
            float mB = fmaxf(fmaxf(b0, b1), b2);
            #pragma unroll
            for (int off = 32; off > 0; off >>= 1) {
                mA = fmaxf(mA, __shfl_xor(mA, off));
                mB = fmaxf(mB, __shfl_xor(mB, off));
            }
            const int lane = t & 63, wid = t >> 6;
            if (lane == 0) { s_red[wid] = mA; s_red[4 + wid] = mB; }
            __syncthreads();
            mA = fmaxf(fmaxf(s_red[0], s_red[1]), fmaxf(s_red[2], s_red[3]));
            mB = fmaxf(fmaxf(s_red[4], s_red[5]), fmaxf(s_red[6], s_red[7]));

            const float pA0 = __expf(a0 - mA), pA1 = __expf(a1 - mA);
            const float pB0 = __expf(b0 - mB), pB1 = __expf(b1 - mB);
            const float pA2 = (t == 0) ? __expf(a2 - mA) : 0.0f;
            const float pB2 = (t == 0) ? __expf(b2 - mB) : 0.0f;
            float sA = pA0 + pA1 + pA2, sB = pB0 + pB1 + pB2;
            #pragma unroll
            for (int off = 32; off > 0; off >>= 1) {
                sA += __shfl_xor(sA, off);
                sB += __shfl_xor(sB, off);
            }
            __syncthreads();
            if (lane == 0) { s_red[8 + wid] = sA; s_red[12 + wid] = sB; }
            __syncthreads();
            sA = s_red[8] + s_red[9] + s_red[10] + s_red[11];
            sB = s_red[12] + s_red[13] + s_red[14] + s_red[15];
            const float iA = 1.0f / sA, iB = 1.0f / sB;

            s_acc[t]       += pA0 * iA + pB0 * iB;
            s_acc[t + 256] += pA1 * iA + pB1 * iB;
            if (t == 0) s_acc[512] += pA2 * iA + pB2 * iB;
        }
    }
    __syncthreads();

    float* Gp = G + (size_t)bh * NF_;
    for (int kk = t; kk < NF_; kk += 256) atomicAdd(&Gp[kk], s_acc[kk]);
}

// Kernel 2: A[b,h,:] = softmax(G[b,h,:]) over 513 bins.
__global__ __launch_bounds__(256) void k_softA(const float* __restrict__ G,
                                               float* __restrict__ A) {
    __shared__ float s_red[16];
    const int bh = blockIdx.x, t = threadIdx.x;
    const float* Gp = G + (size_t)bh * NF_;
    const float g0 = Gp[t];
    const float g1 = Gp[t + 256];
    const float g2 = (t == 0) ? Gp[512] : -1e30f;
    float m = fmaxf(fmaxf(g0, g1), g2);
    #pragma unroll
    for (int off = 32; off > 0; off >>= 1) m = fmaxf(m, __shfl_xor(m, off));
    const int lane = t & 63, wid = t >> 6;
    if (lane == 0) s_red[wid] = m;
    __syncthreads();
    m = fmaxf(fmaxf(s_red[0], s_red[1]), fmaxf(s_red[2], s_red[3]));
    const float p0 = __expf(g0 - m), p1 = __expf(g1 - m);
    const float p2 = (t == 0) ? __expf(g2 - m) : 0.0f;
    float s = p0 + p1 + p2;
    #pragma unroll
    for (int off = 32; off > 0; off >>= 1) s += __shfl_xor(s, off);
    __syncthreads();
    if (lane == 0) s_red[4 + wid] = s;
    __syncthreads();
    s = s_red[4] + s_red[5] + s_red[6] + s_red[7];
    const float inv = 1.0f / s;
    float* Ap = A + (size_t)bh * NF_;
    Ap[t] = p0 * inv;
    Ap[t + 256] = p1 * inv;
    if (t == 0) Ap[512] = p2 * inv;
}

// Kernel 3: block = one (b,h) x 2 e-channels. Stage V at bitrev positions,
// DIT fwd -> natural X; Hermitian manipulation in natural order (conflict-free);
// DIF inverse (natural in -> bitrev out); write Out[l=brev10(pos)].
__global__ __launch_bounds__(256) void k_vfft(const float* __restrict__ V,
                                              const float* __restrict__ A,
                                              float* __restrict__ Out) {
    __shared__ float2 s_z[1024];
    __shared__ float2 s_w[1024];
    __shared__ float2 s_tw[1024];
    __shared__ float s_A[NF_];

    const int t = threadIdx.x;
    const int bid = blockIdx.x;
    const int bh = bid >> 5, ep = bid & 31;
    const int b = bh >> 3, h = bh & 7;
    const int e0 = ep * 2;

    fill_tw(s_tw, t);
    for (int kk = t; kk < NF_; kk += 256) s_A[kk] = A[(size_t)bh * NF_ + kk];
    #pragma unroll
    for (int jj = 0; jj < 4; ++jj) {
        const int s = jj * 256 + t;
        const float* vp = V + (((size_t)b * L_ + s) * H_ + h) * E_ + e0;
        s_z[brev10(s)] = make_float2(vp[0], vp[1]);
    }
    __syncthreads();

    fft_dit(s_z, s_tw, t, -1.0f);   // natural-order X

    #pragma unroll
    for (int jj = 0; jj < 4; ++jj) {
        const int k = jj * 256 + t;
        const int m = (k <= 512) ? k : (N_ - k);
        const float sgn = (k <= 512) ? 1.0f : -1.0f;
        const int mp = (N_ - m) & (N_ - 1);
        const float2 X1 = s_z[m];
        const float2 X2 = s_z[mp];
        const float reV1 = 0.5f * (X1.x + X2.x);
        const float imV1 = 0.5f * (X1.y - X2.y);
        const float reV2 = 0.5f * (X1.y + X2.y);
        const float imV2 = 0.5f * (X2.x - X1.x);
        const float a = s_A[m];
        s_w[k] = make_float2(a * reV1 - sgn * imV2, sgn * imV1 + a * reV2);
    }
    __syncthreads();

    fft_dif(s_w, s_tw, t, +1.0f);   // unnormalized inverse, bitrev output

    const float invN = 1.0f / (float)N_;
    #pragma unroll
    for (int jj = 0; jj < 4; ++jj) {
        const int p = jj * 256 + t;
        const int l = brev10(p);
        const size_t o = (((size_t)b * L_ + l) * E_ + e0) * H_ + h;
        Out[o] = s_w[p].x * invN;        // e0   -> Re
        Out[o + H_] = s_w[p].y * invN;   // e0+1 -> Im
    }
}

extern "C" void kernel_launch(void* const* d_in, const int* in_sizes, int n_in,
                              void* d_out, int out_size, void* d_ws, size_t ws_size,
                              hipStream_t stream) {
    const float* Q = (const float*)d_in[0];
    const float* K = (const float*)d_in[1];
    const float* V = (const float*)d_in[2];
    float* out = (float*)d_out;

    float* ws = (float*)d_ws;
    float* qninv = ws;                       // B*L*H
    float* kninv = qninv + B_ * L_ * H_;     // B*L*H
    float* G     = kninv + B_ * L_ * H_;     // B*H*NF
    float* A     = G + B_ * H_ * NF_;        // B*H*NF

    hipMemsetAsync(G, 0, (size_t)B_ * H_ * NF_ * sizeof(float), stream);
    k_norms<<<(2 * B_ * L_ * H_ + 255) / 256, 256, 0, stream>>>(Q, K, qninv, kninv);
    k_qkfft<<<B_ * H_ * (L_ / 16), 256, 0, stream>>>(Q, K, qninv, kninv, G);
    k_softA<<<B_ * H_, 256, 0, stream>>>(G, A);
    k_vfft<<<B_ * H_ * (E_ / 2), 256, 0, stream>>>(V, A, out);
}